// Round 1
// baseline (71.012 us; speedup 1.0000x reference)
//
#include <hip/hip_runtime.h>
#include <stdint.h>

#define NB 256
#define NQ 900
#define NC 256
#define TOPK 100
#define QC (NQ * NC)      // 230400
#define QC4 (QC / 4)      // 57600
#define NBINS 8192
#define CAP 2048

// fused = exp(-obj) * sigmoid(logit); invalid classes (c>=240) excluded entirely
// (reference forces them to sigmoid(-1e11)=0, which can never enter top-100).

__global__ __launch_bounds__(1024)
void postproc_kernel(const float* __restrict__ logits,
                     const float* __restrict__ obj,
                     const float* __restrict__ pboxes,
                     const float* __restrict__ tsz,
                     float* __restrict__ out)
{
    const int b = blockIdx.x;
    const int tid = threadIdx.x;

    __shared__ unsigned int hist[NBINS];      // 32 KB
    __shared__ float eobj[NQ];                // 3.6 KB
    __shared__ unsigned int cbits[CAP];       // 8 KB
    __shared__ int cidx[CAP];                 // 8 KB
    __shared__ int activeQ[NQ];               // 3.6 KB
    __shared__ unsigned int part[1024];       // 4 KB
    __shared__ unsigned int part2[32];
    __shared__ int s_thrBin;
    __shared__ int s_cnt;
    __shared__ int s_nActive;

    // ---- init ----
    for (int i = tid; i < NBINS; i += 1024) hist[i] = 0;
    if (tid == 0) { s_cnt = 0; s_nActive = 0; }
    if (tid < NQ) eobj[tid] = expf(-obj[b * NQ + tid]);
    __syncthreads();

    const float4* lg4 = (const float4*)(logits + (size_t)b * QC);

    // ---- pass 1: exact histogram of score bit-patterns ----
    for (int i = tid; i < QC4; i += 1024) {
        int f = i & 63;                 // float4 index within row
        if (f >= 60) continue;          // c in [240,256): invalid classes
        float4 v = lg4[i];
        float eo = eobj[i >> 6];
        float s0 = eo * (1.0f / (1.0f + expf(-v.x)));
        float s1 = eo * (1.0f / (1.0f + expf(-v.y)));
        float s2 = eo * (1.0f / (1.0f + expf(-v.z)));
        float s3 = eo * (1.0f / (1.0f + expf(-v.w)));
        atomicAdd(&hist[__float_as_uint(s0) >> 17], 1u);
        atomicAdd(&hist[__float_as_uint(s1) >> 17], 1u);
        atomicAdd(&hist[__float_as_uint(s2) >> 17], 1u);
        atomicAdd(&hist[__float_as_uint(s3) >> 17], 1u);
    }
    __syncthreads();

    // ---- find threshold bin: max T with suffix_count(>=T) >= TOPK ----
    {
        unsigned int sum = 0;
        #pragma unroll
        for (int j = 0; j < 8; ++j) sum += hist[tid * 8 + j];
        part[tid] = sum;
    }
    __syncthreads();
    if (tid < 32) {
        unsigned int s2 = 0;
        #pragma unroll
        for (int j = 0; j < 32; ++j) s2 += part[tid * 32 + j];
        part2[tid] = s2;
    }
    __syncthreads();
    if (tid == 0) {
        int cum = 0;
        int sc = 31;
        while (sc > 0 && cum + (int)part2[sc] < TOPK) { cum += (int)part2[sc]; --sc; }
        int pc = sc * 32 + 31, plo = sc * 32;
        while (pc > plo && cum + (int)part[pc] < TOPK) { cum += (int)part[pc]; --pc; }
        int bin = pc * 8 + 7, blo = pc * 8;
        while (bin > blo && cum + (int)hist[bin] < TOPK) { cum += (int)hist[bin]; --bin; }
        s_thrBin = bin;
    }
    __syncthreads();
    const unsigned int thrBits = (unsigned int)s_thrBin << 17;

    // ---- compact rows that can contain candidates (score <= eobj row bound) ----
    if (tid < NQ) {
        if (__float_as_uint(eobj[tid]) >= thrBits) {
            int p = atomicAdd(&s_nActive, 1);
            activeQ[p] = tid;
        }
    }
    __syncthreads();
    const int nA = s_nActive;

    // ---- pass 2: collect candidates from active rows ----
    // 16 rows / iteration; 64 threads per row, float4 each.
    const int rg = tid >> 6;      // row within group [0,16)
    const int lane = tid & 63;    // float4 within row
    for (int base = 0; base < nA; base += 16) {
        int iq = base + rg;
        if (iq < nA && lane < 60) {
            int q = activeQ[iq];
            float eo = eobj[q];
            float4 v = lg4[(q << 6) + lane];
            #pragma unroll
            for (int j = 0; j < 4; ++j) {
                float x = (j == 0) ? v.x : (j == 1) ? v.y : (j == 2) ? v.z : v.w;
                float s = eo * (1.0f / (1.0f + expf(-x)));
                unsigned int bits = __float_as_uint(s);
                if (bits >= thrBits) {
                    int p = atomicAdd(&s_cnt, 1);
                    if (p < CAP) {
                        cbits[p] = bits;
                        cidx[p] = (q << 8) + (lane << 2) + j;
                    }
                }
            }
        }
    }
    __syncthreads();
    const int M = min(s_cnt, CAP);

    // ---- exact rank selection (desc score, tie -> lower index first) ----
    const float ih = tsz[b * 2 + 0];
    const float iw = tsz[b * 2 + 1];
    float* out_scores = out;
    float* out_labels = out + NB * TOPK;
    float* out_boxes  = out + 2 * NB * TOPK;

    for (int i = tid; i < M; i += 1024) {
        unsigned int mb = cbits[i];
        int mi = cidx[i];
        int rank = 0;
        for (int j = 0; j < M; ++j) {
            unsigned int obp = cbits[j];
            int oi = cidx[j];
            rank += (obp > mb) || (obp == mb && oi < mi);
        }
        if (rank < TOPK) {
            int q = mi >> 8;
            int c = mi & 255;
            out_scores[b * TOPK + rank] = __uint_as_float(mb);
            out_labels[b * TOPK + rank] = (float)c;
            const float* bp = pboxes + ((size_t)b * NQ + q) * 4;
            float cx = bp[0], cy = bp[1], w = bp[2], h = bp[3];
            float* dst = out_boxes + ((size_t)b * TOPK + rank) * 4;
            dst[0] = (cx - 0.5f * w) * iw;
            dst[1] = (cy - 0.5f * h) * ih;
            dst[2] = (cx + 0.5f * w) * iw;
            dst[3] = (cy + 0.5f * h) * ih;
        }
    }
}

extern "C" void kernel_launch(void* const* d_in, const int* in_sizes, int n_in,
                              void* d_out, int out_size, void* d_ws, size_t ws_size,
                              hipStream_t stream) {
    const float* logits = (const float*)d_in[0];
    const float* obj    = (const float*)d_in[1];
    const float* boxes  = (const float*)d_in[2];
    const float* tsz    = (const float*)d_in[3];
    float* out = (float*)d_out;
    hipLaunchKernelGGL(postproc_kernel, dim3(NB), dim3(1024), 0, stream,
                       logits, obj, boxes, tsz, out);
}